// Round 4
// baseline (491.122 us; speedup 1.0000x reference)
//
#include <hip/hip_runtime.h>
#include <hip/hip_bf16.h>
#include <stdint.h>

typedef unsigned short u16;
typedef __bf16 bf16_t;
typedef bf16_t bf16x8 __attribute__((ext_vector_type(8)));
typedef u16 u16x8 __attribute__((ext_vector_type(8)));
typedef u16 u16x4 __attribute__((ext_vector_type(4)));
typedef float f32x4 __attribute__((ext_vector_type(4)));

#define L2E 1.44269504088896f

__device__ __forceinline__ u16 f2bf(float f) {
  uint32_t u = __builtin_bit_cast(uint32_t, f);
  return (u16)((u + 0x7fffu + ((u >> 16) & 1u)) >> 16);
}
__device__ __forceinline__ float bf2f(u16 h) {
  return __builtin_bit_cast(float, (uint32_t)h << 16);
}
__device__ __forceinline__ void split2(float x, u16 &h, u16 &l) {
  h = f2bf(x);
  l = f2bf(x - bf2f(h));
}
__device__ __forceinline__ f32x4 mfma16(u16x8 a, u16x8 b, f32x4 c) {
  return __builtin_amdgcn_mfma_f32_16x16x32_bf16(
      __builtin_bit_cast(bf16x8, a), __builtin_bit_cast(bf16x8, b), c, 0, 0, 0);
}

// ---------------- mask normalize (uint8-bool or int32-bool storage) ----------
__global__ void prep_mask_kernel(const unsigned char *__restrict__ mraw,
                                 float *__restrict__ bias) {
  __shared__ int flag;
  int t = threadIdx.x;
  if (t == 0) flag = 0;
  __syncthreads();
  int local = 0;
  for (int i = t; i < 8192; i += 256)
    if ((i & 3) && mraw[i]) local = 1;
  if (local) atomicOr(&flag, 1);
  __syncthreads();
  const bool bytes = (flag != 0);
  const int *mi = (const int *)mraw;
  for (int i = t; i < 8192; i += 256) {
    int m = bytes ? (int)mraw[i] : mi[i];
    bias[i] = m ? -1e30f : 0.0f;
  }
}

// ---------------- presplit: f32 -> (hi bf16, lo bf16) planar -----------------
__global__ void presplit_kernel(const float *__restrict__ in,
                                u16 *__restrict__ h, u16 *__restrict__ l) {
  int i = (blockIdx.x * 256 + threadIdx.x) * 8;
  f32x4 a = *(const f32x4 *)(in + i);
  f32x4 b = *(const f32x4 *)(in + i + 4);
  u16x8 hh, ll;
#pragma unroll
  for (int e = 0; e < 4; ++e) {
    u16 x, y;
    split2(a[e], x, y); hh[e] = x; ll[e] = y;
    split2(b[e], x, y); hh[4 + e] = x; ll[4 + e] = y;
  }
  *(u16x8 *)(h + i) = hh;
  *(u16x8 *)(l + i) = ll;
}

// ---------------- V transpose: vT[b][m][dd][j] = bf16(x2[b][j][m*256+dd]) ----
__global__ void transpose_v_kernel(const float *__restrict__ x2,
                                   u16 *__restrict__ vT) {
  __shared__ float tile[32][33];
  const int b = blockIdx.z, h0 = blockIdx.y * 32, j0 = blockIdx.x * 32;
  const int tx = threadIdx.x & 31, ty = threadIdx.x >> 5; // 32 x 8
#pragma unroll
  for (int rr = 0; rr < 32; rr += 8)
    tile[ty + rr][tx] = x2[((size_t)b * 1024 + j0 + ty + rr) * 1024 + h0 + tx];
  __syncthreads();
  const int mlev = h0 >> 8, dd0 = h0 & 255;
#pragma unroll
  for (int rr = 0; rr < 32; rr += 8) {
    int dd = dd0 + ty + rr;
    vT[((size_t)(b * 4 + mlev) * 256 + dd) * 1024 + j0 + tx] =
        f2bf(tile[tx][ty + rr]);
  }
}

// ---------------- projection GEMM on pre-split operands ---------------------
// out = relu(A*W^T)[*fv] -> hi/lo bf16. 128x128 tile, BK=32, 4 waves, 48 MFMA/K.
__global__ __launch_bounds__(256, 2) void proj_kernel(
    const u16 *__restrict__ Ahg, const u16 *__restrict__ Alg,
    const u16 *__restrict__ Bhg, const u16 *__restrict__ Blg,
    const float *__restrict__ fv, u16 *__restrict__ outh,
    u16 *__restrict__ outl, int usefv) {
  __shared__ u16 Ah[128 * 40], Al[128 * 40], Bh[128 * 40], Bl[128 * 40];
  const int t = threadIdx.x;
  const int lane = t & 63, wid = t >> 6;
  const int l16 = lane & 15, g = lane >> 4;
  const int wr = wid >> 1, wc = wid & 1;
  const int bm = blockIdx.x, bn = blockIdx.y;

  f32x4 acc[4][4] = {};

  const int srow = t >> 1, c0 = (t & 1) * 16; // u16 cols
  const u16 *aH = Ahg + (size_t)(bm * 128 + srow) * 1024 + c0;
  const u16 *aL = Alg + (size_t)(bm * 128 + srow) * 1024 + c0;
  const u16 *bH = Bhg + (size_t)(bn * 128 + srow) * 1024 + c0;
  const u16 *bL = Blg + (size_t)(bn * 128 + srow) * 1024 + c0;
  const uint32_t off0 = srow * 80 + c0 * 2, off1 = off0 + 16;

  u16x8 rah0 = *(const u16x8 *)(aH), rah1 = *(const u16x8 *)(aH + 8);
  u16x8 ral0 = *(const u16x8 *)(aL), ral1 = *(const u16x8 *)(aL + 8);
  u16x8 rbh0 = *(const u16x8 *)(bH), rbh1 = *(const u16x8 *)(bH + 8);
  u16x8 rbl0 = *(const u16x8 *)(bL), rbl1 = *(const u16x8 *)(bL + 8);

  for (int k0 = 0; k0 < 1024; k0 += 32) {
    __syncthreads(); // previous compute done reading LDS
    *(u16x8 *)((char *)Ah + off0) = rah0; *(u16x8 *)((char *)Ah + off1) = rah1;
    *(u16x8 *)((char *)Al + off0) = ral0; *(u16x8 *)((char *)Al + off1) = ral1;
    *(u16x8 *)((char *)Bh + off0) = rbh0; *(u16x8 *)((char *)Bh + off1) = rbh1;
    *(u16x8 *)((char *)Bl + off0) = rbl0; *(u16x8 *)((char *)Bl + off1) = rbl1;
    __syncthreads(); // staging visible
    if (k0 + 32 < 1024) {
      rah0 = *(const u16x8 *)(aH + k0 + 32); rah1 = *(const u16x8 *)(aH + k0 + 40);
      ral0 = *(const u16x8 *)(aL + k0 + 32); ral1 = *(const u16x8 *)(aL + k0 + 40);
      rbh0 = *(const u16x8 *)(bH + k0 + 32); rbh1 = *(const u16x8 *)(bH + k0 + 40);
      rbl0 = *(const u16x8 *)(bL + k0 + 32); rbl1 = *(const u16x8 *)(bL + k0 + 40);
    }

    u16x8 afh[4], afl[4], bfh[4], bfl[4];
#pragma unroll
    for (int mf = 0; mf < 4; ++mf) {
      int r = wr * 64 + mf * 16 + l16;
      uint32_t off = r * 80 + g * 16;
      afh[mf] = *(const u16x8 *)((const char *)Ah + off);
      afl[mf] = *(const u16x8 *)((const char *)Al + off);
    }
#pragma unroll
    for (int nf = 0; nf < 4; ++nf) {
      int r = wc * 64 + nf * 16 + l16;
      uint32_t off = r * 80 + g * 16;
      bfh[nf] = *(const u16x8 *)((const char *)Bh + off);
      bfl[nf] = *(const u16x8 *)((const char *)Bl + off);
    }
    __builtin_amdgcn_s_setprio(1);
#pragma unroll
    for (int mf = 0; mf < 4; ++mf)
#pragma unroll
      for (int nf = 0; nf < 4; ++nf) {
        acc[mf][nf] = mfma16(afh[mf], bfh[nf], acc[mf][nf]);
        acc[mf][nf] = mfma16(afh[mf], bfl[nf], acc[mf][nf]);
        acc[mf][nf] = mfma16(afl[mf], bfh[nf], acc[mf][nf]);
      }
    __builtin_amdgcn_s_setprio(0);
  }

#pragma unroll
  for (int nf = 0; nf < 4; ++nf) {
    int col = bn * 128 + wc * 64 + nf * 16 + l16;
    float f = usefv ? fv[col] : 1.0f;
#pragma unroll
    for (int mf = 0; mf < 4; ++mf) {
      int row0 = bm * 128 + wr * 64 + mf * 16 + g * 4;
#pragma unroll
      for (int q = 0; q < 4; ++q) {
        float v = acc[mf][nf][q];
        v = (v > 0.f ? v : 0.f) * f;
        u16 hh, ll;
        split2(v, hh, ll);
        size_t idx = (size_t)(row0 + q) * 1024 + col;
        outh[idx] = hh;
        outl[idx] = ll;
      }
    }
  }
}

// ---------------- fused flash attention -------------------------------------
// 1 block/CU: 128 Q rows (4 waves x 32 = 2 M-frags), K-tile 32, double-buffered
// LDS, single barrier per jt, loads issued 2 tiles ahead.
__global__ __launch_bounds__(256, 1) void attn_kernel(
    const u16 *__restrict__ x1kh, const u16 *__restrict__ x1kl,
    const u16 *__restrict__ x2kh, const u16 *__restrict__ x2kl,
    const u16 *__restrict__ vT, const float *__restrict__ bias,
    float *__restrict__ out) {
  __shared__ u16 K2h[2][32 * 256], K2l[2][32 * 256]; // 16KB each buf
  __shared__ u16 VTs[2][256 * 32];                   // 16KB each buf
  __shared__ float biasS[1024];
  __shared__ u16 P[4][2][16 * 36]; // per-wave, per-frag, row stride 72B

  const int t = threadIdx.x;
  const int lane = t & 63, wid = t >> 6;
  const int l16 = lane & 15, g = lane >> 4;
  // XCD-aware decode: keep all 8 it-blocks of one (b,m) on one XCD
  const int id = blockIdx.x;       // 0..255
  const int xcd = id & 7, idx = id >> 3;
  const int it = idx & 7, ps = idx >> 3;
  const int pair = xcd + 8 * ps;   // 0..31
  const int b = pair >> 2, m = pair & 3;

  for (int j = t; j < 1024; j += 256) biasS[j] = bias[b * 1024 + j];

  // Q hoist: 2 frags x 8 dk, hi+lo
  u16x8 Qh[2][8], Ql[2][8];
#pragma unroll
  for (int f = 0; f < 2; ++f) {
    const int qrow = it * 128 + wid * 32 + f * 16 + l16;
    const size_t base = ((size_t)b * 1024 + qrow) * 1024 + m * 256;
#pragma unroll
    for (int dk = 0; dk < 8; ++dk) {
      Qh[f][dk] = *(const u16x8 *)(x1kh + base + dk * 32 + g * 8);
      Ql[f][dk] = *(const u16x8 *)(x1kl + base + dk * 32 + g * 8);
    }
  }

  f32x4 acc[2][16] = {};
  float mrow[2][4], lrow[2][4];
#pragma unroll
  for (int f = 0; f < 2; ++f)
#pragma unroll
    for (int r = 0; r < 4; ++r) { mrow[f][r] = -1e30f; lrow[f][r] = 0.f; }

  // staging geometry (unchanged, bank-uniform)
  const int sj = t >> 3;
  const u16 *khsrc = x2kh + ((size_t)b * 1024 + sj) * 1024 + m * 256 + (t & 7) * 32;
  const u16 *klsrc = x2kl + ((size_t)b * 1024 + sj) * 1024 + m * 256 + (t & 7) * 32;
  const u16 *vtsrc = vT + ((size_t)((b * 4 + m) * 256 + t)) * 1024;
  uint32_t koff[4], voff[4];
#pragma unroll
  for (int q = 0; q < 4; ++q) {
    koff[q] = sj * 512 + ((((t & 7) * 64) + q * 16) ^ ((sj & 7) << 4));
    voff[q] = t * 64 + ((q * 16) ^ ((t & 3) << 4));
  }

  u16x8 pk_h[4], pk_l[4], pv[4];
#pragma unroll
  for (int q = 0; q < 4; ++q) { // tile 0
    pk_h[q] = *(const u16x8 *)(khsrc + q * 8);
    pk_l[q] = *(const u16x8 *)(klsrc + q * 8);
    pv[q] = *(const u16x8 *)(vtsrc + q * 8);
  }
#pragma unroll
  for (int q = 0; q < 4; ++q) { // write buf0
    *(u16x8 *)((char *)K2h[0] + koff[q]) = pk_h[q];
    *(u16x8 *)((char *)K2l[0] + koff[q]) = pk_l[q];
    *(u16x8 *)((char *)VTs[0] + voff[q]) = pv[q];
  }
#pragma unroll
  for (int q = 0; q < 4; ++q) { // tile 1 into regs
    pk_h[q] = *(const u16x8 *)(khsrc + 32 * 1024 + q * 8);
    pk_l[q] = *(const u16x8 *)(klsrc + 32 * 1024 + q * 8);
    pv[q] = *(const u16x8 *)(vtsrc + 32 + q * 8);
  }
  __syncthreads();

  for (int jt = 0; jt < 32; ++jt) {
    const int cur = jt & 1;
    const int j0 = jt * 32;
    const char *KHc = (const char *)K2h[cur];
    const char *KLc = (const char *)K2l[cur];

    // QK^T: 2 frags x 2 j-halves, 3-term split, 96 MFMA
    f32x4 s[2][2] = {};
    __builtin_amdgcn_s_setprio(1);
#pragma unroll
    for (int jh = 0; jh < 2; ++jh) {
      const int j = jh * 16 + l16;
      const uint32_t kxo = ((j & 7) << 4);
      const char *rowH = KHc + j * 512;
      const char *rowL = KLc + j * 512;
#pragma unroll
      for (int dk = 0; dk < 8; ++dk) {
        uint32_t off = (uint32_t)(dk * 64 + g * 16) ^ kxo;
        u16x8 kh = *(const u16x8 *)(rowH + off);
        u16x8 kl = *(const u16x8 *)(rowL + off);
        s[0][jh] = mfma16(Qh[0][dk], kh, s[0][jh]);
        s[1][jh] = mfma16(Qh[1][dk], kh, s[1][jh]);
        s[0][jh] = mfma16(Ql[0][dk], kh, s[0][jh]);
        s[1][jh] = mfma16(Ql[1][dk], kh, s[1][jh]);
        s[0][jh] = mfma16(Qh[0][dk], kl, s[0][jh]);
        s[1][jh] = mfma16(Qh[1][dk], kl, s[1][jh]);
      }
    }
    __builtin_amdgcn_s_setprio(0);

    // online softmax per frag
    const float bj0 = biasS[j0 + l16], bj1 = biasS[j0 + 16 + l16];
    float p[2][2][4];
#pragma unroll
    for (int f = 0; f < 2; ++f) {
      float sv0[4], sv1[4], tm[4];
#pragma unroll
      for (int r = 0; r < 4; ++r) {
        sv0[r] = s[f][0][r] + bj0;
        sv1[r] = s[f][1][r] + bj1;
        tm[r] = fmaxf(sv0[r], sv1[r]);
      }
#pragma unroll
      for (int d = 1; d < 16; d <<= 1)
#pragma unroll
        for (int r = 0; r < 4; ++r) tm[r] = fmaxf(tm[r], __shfl_xor(tm[r], d, 64));
      float sc[4], rs[4];
#pragma unroll
      for (int r = 0; r < 4; ++r) {
        float nm = fmaxf(mrow[f][r], tm[r]);
        sc[r] = exp2f((mrow[f][r] - nm) * L2E);
        mrow[f][r] = nm;
        p[f][0][r] = exp2f((sv0[r] - nm) * L2E);
        p[f][1][r] = exp2f((sv1[r] - nm) * L2E);
        rs[r] = p[f][0][r] + p[f][1][r];
      }
#pragma unroll
      for (int d = 1; d < 16; d <<= 1)
#pragma unroll
        for (int r = 0; r < 4; ++r) rs[r] += __shfl_xor(rs[r], d, 64);
#pragma unroll
      for (int r = 0; r < 4; ++r) lrow[f][r] = lrow[f][r] * sc[r] + rs[r];
#pragma unroll
      for (int nf = 0; nf < 16; ++nf)
#pragma unroll
        for (int r = 0; r < 4; ++r) acc[f][nf][r] *= sc[r];
    }

    // write next tile (jt+1) from regs into buf[cur^1]
    if (jt < 31) {
      char *KHn = (char *)K2h[cur ^ 1];
      char *KLn = (char *)K2l[cur ^ 1];
      char *VTn = (char *)VTs[cur ^ 1];
#pragma unroll
      for (int q = 0; q < 4; ++q) {
        *(u16x8 *)(KHn + koff[q]) = pk_h[q];
        *(u16x8 *)(KLn + koff[q]) = pk_l[q];
        *(u16x8 *)(VTn + voff[q]) = pv[q];
      }
    }
    // issue loads for jt+2 (latency hidden under PV + next QK)
    if (jt < 30) {
      const size_t o = (size_t)(jt + 2) * 32 * 1024;
#pragma unroll
      for (int q = 0; q < 4; ++q) {
        pk_h[q] = *(const u16x8 *)(khsrc + o + q * 8);
        pk_l[q] = *(const u16x8 *)(klsrc + o + q * 8);
        pv[q] = *(const u16x8 *)(vtsrc + (jt + 2) * 32 + q * 8);
      }
    }

    // P -> per-wave LDS (bf16), then PV for both frags
#pragma unroll
    for (int f = 0; f < 2; ++f) {
      u16 *Pw = &P[wid][f][0];
#pragma unroll
      for (int sub = 0; sub < 2; ++sub)
#pragma unroll
        for (int r = 0; r < 4; ++r) {
          int il = g * 4 + r, jl = sub * 16 + l16;
          Pw[il * 36 + jl] = f2bf(p[f][sub][r]);
        }
    }
    u16x8 pa[2];
#pragma unroll
    for (int f = 0; f < 2; ++f) {
      const u16 *pp = &P[wid][f][0] + l16 * 36 + g * 8;
      u16x4 a0 = *(const u16x4 *)(pp);
      u16x4 a1 = *(const u16x4 *)(pp + 4);
      pa[f] = __builtin_shufflevector(a0, a1, 0, 1, 2, 3, 4, 5, 6, 7);
    }
    const char *VTc = (const char *)VTs[cur];
    __builtin_amdgcn_s_setprio(1);
#pragma unroll
    for (int nf = 0; nf < 16; ++nf) {
      int dd = nf * 16 + l16;
      uint32_t off = dd * 64 + ((g * 16) ^ ((dd & 3) << 4));
      u16x8 bb = *(const u16x8 *)(VTc + off);
      acc[0][nf] = mfma16(pa[0], bb, acc[0][nf]);
      acc[1][nf] = mfma16(pa[1], bb, acc[1][nf]);
    }
    __builtin_amdgcn_s_setprio(0);
    __syncthreads();
  }

  float inv[2][4];
#pragma unroll
  for (int f = 0; f < 2; ++f)
#pragma unroll
    for (int r = 0; r < 4; ++r) inv[f][r] = 1.0f / lrow[f][r];
#pragma unroll
  for (int f = 0; f < 2; ++f)
#pragma unroll
    for (int nf = 0; nf < 16; ++nf) {
      int col = m * 256 + nf * 16 + l16;
#pragma unroll
      for (int r = 0; r < 4; ++r) {
        int row = it * 128 + wid * 32 + f * 16 + g * 4 + r;
        out[((size_t)b * 1024 + row) * 1024 + col] = acc[f][nf][r] * inv[f][r];
      }
    }
}

// ---------------- launch ----------------------------------------------------
extern "C" void kernel_launch(void *const *d_in, const int *in_sizes, int n_in,
                              void *d_out, int out_size, void *d_ws,
                              size_t ws_size, hipStream_t stream) {
  const float *x1_att = (const float *)d_in[0];
  const float *x2_att = (const float *)d_in[1];
  const float *x2 = (const float *)d_in[2];
  const unsigned char *mask = (const unsigned char *)d_in[3];
  const float *W = (const float *)d_in[4];
  const float *fv = (const float *)d_in[5];
  float *out = (float *)d_out;

  const size_t MB = 1u << 20;
  char *ws = (char *)d_ws;
  u16 *x1ah = (u16 *)(ws + 0 * MB);    // 16MB
  u16 *x1al = (u16 *)(ws + 16 * MB);   // 16MB
  u16 *x2ah = (u16 *)(ws + 32 * MB);   // 16MB
  u16 *x2al = (u16 *)(ws + 48 * MB);   // 16MB
  u16 *Wh = (u16 *)(ws + 64 * MB);     // 2MB
  u16 *Wl = (u16 *)(ws + 66 * MB);     // 2MB
  float *bias = (float *)(ws + 68 * MB); // 32KB
  u16 *x1kh = (u16 *)(ws + 69 * MB);   // 16MB
  u16 *x1kl = (u16 *)(ws + 85 * MB);   // 16MB -> peak 101MB
  u16 *x2kh = (u16 *)(ws + 0 * MB);    // alias x1ah (dead after proj1)
  u16 *x2kl = (u16 *)(ws + 16 * MB);   // alias x1al
  u16 *vT = (u16 *)(ws + 48 * MB);     // alias x2al (dead after proj2)

  prep_mask_kernel<<<dim3(1), dim3(256), 0, stream>>>(mask, bias);
  presplit_kernel<<<dim3(4096), dim3(256), 0, stream>>>(x1_att, x1ah, x1al);
  presplit_kernel<<<dim3(4096), dim3(256), 0, stream>>>(x2_att, x2ah, x2al);
  presplit_kernel<<<dim3(512), dim3(256), 0, stream>>>(W, Wh, Wl);
  proj_kernel<<<dim3(64, 8), dim3(256), 0, stream>>>(x1ah, x1al, Wh, Wl, fv,
                                                     x1kh, x1kl, 0);
  proj_kernel<<<dim3(64, 8), dim3(256), 0, stream>>>(x2ah, x2al, Wh, Wl, fv,
                                                     x2kh, x2kl, 1);
  transpose_v_kernel<<<dim3(32, 32, 8), dim3(256), 0, stream>>>(x2, vT);
  attn_kernel<<<dim3(256), dim3(256), 0, stream>>>(x1kh, x1kl, x2kh, x2kl, vT,
                                                   bias, out);
}

// Round 5
// 326.088 us; speedup vs baseline: 1.5061x; 1.5061x over previous
//
#include <hip/hip_runtime.h>
#include <hip/hip_bf16.h>
#include <stdint.h>

typedef unsigned short u16;
typedef _Float16 f16_t;
typedef f16_t f16x8 __attribute__((ext_vector_type(8)));
typedef u16 u16x8 __attribute__((ext_vector_type(8)));
typedef u16 u16x4 __attribute__((ext_vector_type(4)));
typedef float f32x4 __attribute__((ext_vector_type(4)));

#define L2E 1.44269504088896f
#define DEFER_THR 7.0f // log2 units: skipped-rescale p bounded by 2^7 = 128

__device__ __forceinline__ u16 f2h(float f) {
  f16_t h = (f16_t)f;
  return __builtin_bit_cast(u16, h);
}
__device__ __forceinline__ f32x4 mfma16h(u16x8 a, u16x8 b, f32x4 c) {
  return __builtin_amdgcn_mfma_f32_16x16x32_f16(
      __builtin_bit_cast(f16x8, a), __builtin_bit_cast(f16x8, b), c, 0, 0, 0);
}

// ---------------- mask normalize (uint8-bool or int32-bool storage) ----------
__global__ void prep_mask_kernel(const unsigned char *__restrict__ mraw,
                                 float *__restrict__ bias) {
  __shared__ int flag;
  int t = threadIdx.x;
  if (t == 0) flag = 0;
  __syncthreads();
  int local = 0;
  for (int i = t; i < 8192; i += 256)
    if ((i & 3) && mraw[i]) local = 1;
  if (local) atomicOr(&flag, 1);
  __syncthreads();
  const bool bytes = (flag != 0);
  const int *mi = (const int *)mraw;
  for (int i = t; i < 8192; i += 256) {
    int m = bytes ? (int)mraw[i] : mi[i];
    bias[i] = m ? -1e30f : 0.0f;
  }
}

// ---------------- f32 -> fp16 convert ---------------------------------------
__global__ void cvt_f16_kernel(const float *__restrict__ in,
                               u16 *__restrict__ out) {
  int i = (blockIdx.x * 256 + threadIdx.x) * 8;
  f32x4 a = *(const f32x4 *)(in + i);
  f32x4 b = *(const f32x4 *)(in + i + 4);
  u16x8 o;
#pragma unroll
  for (int e = 0; e < 4; ++e) {
    o[e] = f2h(a[e]);
    o[4 + e] = f2h(b[e]);
  }
  *(u16x8 *)(out + i) = o;
}

// ---------------- V transpose: vT[b][m][dd][j] = fp16(x2[b][j][m*256+dd]) ----
__global__ void transpose_v_kernel(const float *__restrict__ x2,
                                   u16 *__restrict__ vT) {
  __shared__ float tile[32][33];
  const int b = blockIdx.z, h0 = blockIdx.y * 32, j0 = blockIdx.x * 32;
  const int tx = threadIdx.x & 31, ty = threadIdx.x >> 5; // 32 x 8
#pragma unroll
  for (int rr = 0; rr < 32; rr += 8)
    tile[ty + rr][tx] = x2[((size_t)b * 1024 + j0 + ty + rr) * 1024 + h0 + tx];
  __syncthreads();
  const int mlev = h0 >> 8, dd0 = h0 & 255;
#pragma unroll
  for (int rr = 0; rr < 32; rr += 8) {
    int dd = dd0 + ty + rr;
    vT[((size_t)(b * 4 + mlev) * 256 + dd) * 1024 + j0 + tx] =
        f2h(tile[tx][ty + rr]);
  }
}

// ---------------- fp16 projection GEMM: out = fp16(relu(A*W^T)[*fv]) --------
// 128x128 tile, BK=32, 4 waves (2x2 of 64x64), 16 MFMA/K-step, reg prefetch.
__global__ __launch_bounds__(256, 2) void proj_kernel(
    const u16 *__restrict__ Ag, const u16 *__restrict__ Bg,
    const float *__restrict__ fv, u16 *__restrict__ outk, int usefv) {
  __shared__ u16 As[128 * 40], Bs[128 * 40]; // row stride 80B (32 data + pad)
  const int t = threadIdx.x;
  const int lane = t & 63, wid = t >> 6;
  const int l16 = lane & 15, g = lane >> 4;
  const int wr = wid >> 1, wc = wid & 1;
  const int bm = blockIdx.x, bn = blockIdx.y;

  f32x4 acc[4][4] = {};

  const int srow = t >> 1, c0 = (t & 1) * 16; // u16 cols
  const u16 *aS = Ag + (size_t)(bm * 128 + srow) * 1024 + c0;
  const u16 *bS = Bg + (size_t)(bn * 128 + srow) * 1024 + c0;
  const uint32_t off0 = srow * 80 + c0 * 2, off1 = off0 + 16;

  u16x8 ra0 = *(const u16x8 *)(aS), ra1 = *(const u16x8 *)(aS + 8);
  u16x8 rb0 = *(const u16x8 *)(bS), rb1 = *(const u16x8 *)(bS + 8);

  for (int k0 = 0; k0 < 1024; k0 += 32) {
    __syncthreads(); // previous compute done reading LDS
    *(u16x8 *)((char *)As + off0) = ra0;
    *(u16x8 *)((char *)As + off1) = ra1;
    *(u16x8 *)((char *)Bs + off0) = rb0;
    *(u16x8 *)((char *)Bs + off1) = rb1;
    __syncthreads(); // staging visible
    if (k0 + 32 < 1024) { // prefetch next K-tile
      ra0 = *(const u16x8 *)(aS + k0 + 32);
      ra1 = *(const u16x8 *)(aS + k0 + 40);
      rb0 = *(const u16x8 *)(bS + k0 + 32);
      rb1 = *(const u16x8 *)(bS + k0 + 40);
    }

    u16x8 af[4], bf[4];
#pragma unroll
    for (int mf = 0; mf < 4; ++mf) {
      int r = wr * 64 + mf * 16 + l16;
      af[mf] = *(const u16x8 *)((const char *)As + r * 80 + g * 16);
    }
#pragma unroll
    for (int nf = 0; nf < 4; ++nf) {
      int r = wc * 64 + nf * 16 + l16;
      bf[nf] = *(const u16x8 *)((const char *)Bs + r * 80 + g * 16);
    }
    __builtin_amdgcn_s_setprio(1);
#pragma unroll
    for (int mf = 0; mf < 4; ++mf)
#pragma unroll
      for (int nf = 0; nf < 4; ++nf)
        acc[mf][nf] = mfma16h(af[mf], bf[nf], acc[mf][nf]);
    __builtin_amdgcn_s_setprio(0);
  }

#pragma unroll
  for (int nf = 0; nf < 4; ++nf) {
    int col = bn * 128 + wc * 64 + nf * 16 + l16;
    float f = usefv ? fv[col] : 1.0f;
#pragma unroll
    for (int mf = 0; mf < 4; ++mf) {
      int row0 = bm * 128 + wr * 64 + mf * 16 + g * 4;
#pragma unroll
      for (int q = 0; q < 4; ++q) {
        float v = acc[mf][nf][q];
        v = (v > 0.f ? v : 0.f) * f;
        outk[(size_t)(row0 + q) * 1024 + col] = f2h(v);
      }
    }
  }
}

// ---------------- fused flash attention (fp16, defer-max) -------------------
// Round-3 geometry: 512 blocks (2/CU), 4 waves x 16 Q rows, K-tile 32,
// single LDS buffer + register prefetch, 16 QK + 16 PV MFMA per jt.
__global__ __launch_bounds__(256, 2) void attn_kernel(
    const u16 *__restrict__ x1k, const u16 *__restrict__ x2k,
    const u16 *__restrict__ vT, const float *__restrict__ bias,
    float *__restrict__ out) {
  __shared__ u16 K2s[32 * 256]; // 16KB, 16B-gran XOR swz
  __shared__ u16 VTs[256 * 32]; // 16KB, 16B-gran XOR swz
  __shared__ float biasS[1024];
  __shared__ u16 P[4][16 * 36]; // per-wave P tile, row stride 72B

  const int t = threadIdx.x;
  const int lane = t & 63, wid = t >> 6;
  const int l16 = lane & 15, g = lane >> 4;
  // XCD-aware decode: all 16 it-blocks of one (b,m) on one XCD
  const int id = blockIdx.x; // 0..511
  const int xcd = id & 7, idx = id >> 3;
  const int it = idx & 15, pp = idx >> 4; // pp 0..3
  const int pair = xcd + 8 * pp;          // 0..31
  const int b = pair >> 2, m = pair & 3;

  for (int j = t; j < 1024; j += 256) biasS[j] = bias[b * 1024 + j];

  // Q hoist: A-frag rows = l16, k = dk*32 + g*8 + e
  const int qrow = it * 64 + wid * 16 + l16;
  const u16 *qsrc = x1k + ((size_t)b * 1024 + qrow) * 1024 + m * 256;
  u16x8 Q[8];
#pragma unroll
  for (int dk = 0; dk < 8; ++dk) Q[dk] = *(const u16x8 *)(qsrc + dk * 32 + g * 8);

  f32x4 acc[16] = {};
  float mrow[4] = {-1e30f, -1e30f, -1e30f, -1e30f};
  float lrow[4] = {0.f, 0.f, 0.f, 0.f};

  // staging geometry (bank-uniform, bijective swizzles)
  const int sj = t >> 3;
  const u16 *ksrc = x2k + ((size_t)b * 1024 + sj) * 1024 + m * 256 + (t & 7) * 32;
  const u16 *vtsrc = vT + ((size_t)((b * 4 + m) * 256 + t)) * 1024;
  uint32_t koff[4], voff[4];
#pragma unroll
  for (int q = 0; q < 4; ++q) {
    koff[q] = sj * 512 + ((((t & 7) * 64) + q * 16) ^ ((sj & 7) << 4));
    voff[q] = t * 64 + ((q * 16) ^ ((t & 3) << 4));
  }

  u16x8 pk[4], pv[4];
#pragma unroll
  for (int q = 0; q < 4; ++q) {
    pk[q] = *(const u16x8 *)(ksrc + q * 8);
    pv[q] = *(const u16x8 *)(vtsrc + q * 8);
  }

  for (int jt = 0; jt < 32; ++jt) {
    const int j0 = jt * 32;
    __syncthreads(); // prev compute done reading LDS
#pragma unroll
    for (int q = 0; q < 4; ++q) {
      *(u16x8 *)((char *)K2s + koff[q]) = pk[q];
      *(u16x8 *)((char *)VTs + voff[q]) = pv[q];
    }
    __syncthreads(); // staging visible
    if (jt < 31) { // prefetch next tile (latency hidden under compute)
      const u16 *k2 = ksrc + (size_t)(jt + 1) * 32 * 1024;
      const u16 *v2 = vtsrc + (jt + 1) * 32;
#pragma unroll
      for (int q = 0; q < 4; ++q) {
        pk[q] = *(const u16x8 *)(k2 + q * 8);
        pv[q] = *(const u16x8 *)(v2 + q * 8);
      }
    }

    // QK^T: rows i=g*4+r, cols j=l16 (+16), 16 MFMA
    f32x4 s0 = {0.f, 0.f, 0.f, 0.f}, s1 = {0.f, 0.f, 0.f, 0.f};
    __builtin_amdgcn_s_setprio(1);
    {
      const int j = l16;
      const uint32_t kxo = ((j & 7) << 4);
      const char *row = (const char *)K2s + j * 512;
#pragma unroll
      for (int dk = 0; dk < 8; ++dk) {
        u16x8 kk = *(const u16x8 *)(row + ((uint32_t)(dk * 64 + g * 16) ^ kxo));
        s0 = mfma16h(Q[dk], kk, s0);
      }
    }
    {
      const int j = 16 + l16;
      const uint32_t kxo = ((j & 7) << 4);
      const char *row = (const char *)K2s + j * 512;
#pragma unroll
      for (int dk = 0; dk < 8; ++dk) {
        u16x8 kk = *(const u16x8 *)(row + ((uint32_t)(dk * 64 + g * 16) ^ kxo));
        s1 = mfma16h(Q[dk], kk, s1);
      }
    }
    __builtin_amdgcn_s_setprio(0);

    // online softmax with defer-max (T13)
    float sv0[4], sv1[4], tm[4];
    const float bj0 = biasS[j0 + l16], bj1 = biasS[j0 + 16 + l16];
#pragma unroll
    for (int r = 0; r < 4; ++r) {
      sv0[r] = s0[r] + bj0;
      sv1[r] = s1[r] + bj1;
      tm[r] = fmaxf(sv0[r], sv1[r]);
    }
#pragma unroll
    for (int d = 1; d < 16; d <<= 1)
#pragma unroll
      for (int r = 0; r < 4; ++r) tm[r] = fmaxf(tm[r], __shfl_xor(tm[r], d, 64));
    bool need = false;
#pragma unroll
    for (int r = 0; r < 4; ++r)
      need = need || ((tm[r] - mrow[r]) * L2E > DEFER_THR);
    if (__any((int)need)) {
#pragma unroll
      for (int r = 0; r < 4; ++r) {
        float nm = fmaxf(mrow[r], tm[r]);
        float sc = exp2f((mrow[r] - nm) * L2E);
        mrow[r] = nm;
        lrow[r] *= sc;
#pragma unroll
        for (int nf = 0; nf < 16; ++nf) acc[nf][r] *= sc;
      }
    }
    float p0[4], p1[4], rs[4];
#pragma unroll
    for (int r = 0; r < 4; ++r) {
      p0[r] = exp2f((sv0[r] - mrow[r]) * L2E);
      p1[r] = exp2f((sv1[r] - mrow[r]) * L2E);
      rs[r] = p0[r] + p1[r];
    }
#pragma unroll
    for (int d = 1; d < 16; d <<= 1)
#pragma unroll
      for (int r = 0; r < 4; ++r) rs[r] += __shfl_xor(rs[r], d, 64);
#pragma unroll
    for (int r = 0; r < 4; ++r) lrow[r] += rs[r];

    // P -> per-wave LDS (fp16), then PV
    u16 *Pw = &P[wid][0];
#pragma unroll
    for (int r = 0; r < 4; ++r) {
      int il = g * 4 + r;
      Pw[il * 36 + l16] = f2h(p0[r]);
      Pw[il * 36 + 16 + l16] = f2h(p1[r]);
    }
    u16x8 pa;
    {
      const u16 *pp2 = Pw + l16 * 36 + g * 8;
      u16x4 a0 = *(const u16x4 *)(pp2);
      u16x4 a1 = *(const u16x4 *)(pp2 + 4);
      pa = __builtin_shufflevector(a0, a1, 0, 1, 2, 3, 4, 5, 6, 7);
    }
    __builtin_amdgcn_s_setprio(1);
#pragma unroll
    for (int nf = 0; nf < 16; ++nf) {
      int dd = nf * 16 + l16;
      uint32_t off = dd * 64 + ((g * 16) ^ ((dd & 3) << 4));
      u16x8 bb = *(const u16x8 *)((const char *)VTs + off);
      acc[nf] = mfma16h(pa, bb, acc[nf]);
    }
    __builtin_amdgcn_s_setprio(0);
  }

  float inv[4];
#pragma unroll
  for (int r = 0; r < 4; ++r) inv[r] = 1.0f / lrow[r];
#pragma unroll
  for (int nf = 0; nf < 16; ++nf) {
    int col = m * 256 + nf * 16 + l16;
#pragma unroll
    for (int r = 0; r < 4; ++r) {
      int row = it * 64 + wid * 16 + g * 4 + r;
      out[((size_t)b * 1024 + row) * 1024 + col] = acc[nf][r] * inv[r];
    }
  }
}

// ---------------- launch ----------------------------------------------------
extern "C" void kernel_launch(void *const *d_in, const int *in_sizes, int n_in,
                              void *d_out, int out_size, void *d_ws,
                              size_t ws_size, hipStream_t stream) {
  const float *x1_att = (const float *)d_in[0];
  const float *x2_att = (const float *)d_in[1];
  const float *x2 = (const float *)d_in[2];
  const unsigned char *mask = (const unsigned char *)d_in[3];
  const float *W = (const float *)d_in[4];
  const float *fv = (const float *)d_in[5];
  float *out = (float *)d_out;

  const size_t MB = 1u << 20;
  char *ws = (char *)d_ws;
  u16 *x1a16 = (u16 *)(ws + 0 * MB);   // 16MB
  u16 *x2a16 = (u16 *)(ws + 16 * MB);  // 16MB
  u16 *W16 = (u16 *)(ws + 32 * MB);    // 2MB
  u16 *x1k = (u16 *)(ws + 34 * MB);    // 16MB
  u16 *x2k = (u16 *)(ws + 50 * MB);    // 16MB
  u16 *vT = (u16 *)(ws + 66 * MB);     // 16MB
  float *bias = (float *)(ws + 82 * MB); // 32KB

  prep_mask_kernel<<<dim3(1), dim3(256), 0, stream>>>(mask, bias);
  cvt_f16_kernel<<<dim3(4096), dim3(256), 0, stream>>>(x1_att, x1a16);
  cvt_f16_kernel<<<dim3(4096), dim3(256), 0, stream>>>(x2_att, x2a16);
  cvt_f16_kernel<<<dim3(512), dim3(256), 0, stream>>>(W, W16);
  proj_kernel<<<dim3(64, 8), dim3(256), 0, stream>>>(x1a16, W16, fv, x1k, 0);
  proj_kernel<<<dim3(64, 8), dim3(256), 0, stream>>>(x2a16, W16, fv, x2k, 1);
  transpose_v_kernel<<<dim3(32, 32, 8), dim3(256), 0, stream>>>(x2, vT);
  attn_kernel<<<dim3(512), dim3(256), 0, stream>>>(x1k, x2k, vT, bias, out);
}

// Round 6
// 323.498 us; speedup vs baseline: 1.5182x; 1.0080x over previous
//
#include <hip/hip_runtime.h>
#include <hip/hip_bf16.h>
#include <stdint.h>

typedef unsigned short u16;
typedef _Float16 f16_t;
typedef f16_t f16x8 __attribute__((ext_vector_type(8)));
typedef u16 u16x8 __attribute__((ext_vector_type(8)));
typedef u16 u16x4 __attribute__((ext_vector_type(4)));
typedef float f32x4 __attribute__((ext_vector_type(4)));

#define L2E 1.44269504088896f
#define DEFER_THR 7.0f

__device__ __forceinline__ u16 f2h(float f) {
  f16_t h = (f16_t)f;
  return __builtin_bit_cast(u16, h);
}
__device__ __forceinline__ f32x4 mfma16h(u16x8 a, u16x8 b, f32x4 c) {
  return __builtin_amdgcn_mfma_f32_16x16x32_f16(
      __builtin_bit_cast(f16x8, a), __builtin_bit_cast(f16x8, b), c, 0, 0, 0);
}
__device__ __forceinline__ void gl16(const u16 *g, u16 *l) {
  __builtin_amdgcn_global_load_lds(
      (const __attribute__((address_space(1))) void *)g,
      (__attribute__((address_space(3))) void *)l, 16, 0, 0);
}

// ---------------- mask normalize (uint8-bool or int32-bool storage) ----------
__global__ void prep_mask_kernel(const unsigned char *__restrict__ mraw,
                                 float *__restrict__ bias) {
  __shared__ int flag;
  int t = threadIdx.x;
  if (t == 0) flag = 0;
  __syncthreads();
  int local = 0;
  for (int i = t; i < 8192; i += 256)
    if ((i & 3) && mraw[i]) local = 1;
  if (local) atomicOr(&flag, 1);
  __syncthreads();
  const bool bytes = (flag != 0);
  const int *mi = (const int *)mraw;
  for (int i = t; i < 8192; i += 256) {
    int m = bytes ? (int)mraw[i] : mi[i];
    bias[i] = m ? -1e30f : 0.0f;
  }
}

// ---------------- f32 -> fp16 convert ---------------------------------------
__global__ void cvt_f16_kernel(const float *__restrict__ in,
                               u16 *__restrict__ out) {
  int i = (blockIdx.x * 256 + threadIdx.x) * 8;
  f32x4 a = *(const f32x4 *)(in + i);
  f32x4 b = *(const f32x4 *)(in + i + 4);
  u16x8 o;
#pragma unroll
  for (int e = 0; e < 4; ++e) {
    o[e] = f2h(a[e]);
    o[4 + e] = f2h(b[e]);
  }
  *(u16x8 *)(out + i) = o;
}

// ---------------- V transpose: vT[b][m][dd][j] = fp16(x2[b][j][m*256+dd]) ----
__global__ void transpose_v_kernel(const float *__restrict__ x2,
                                   u16 *__restrict__ vT) {
  __shared__ float tile[32][33];
  const int b = blockIdx.z, h0 = blockIdx.y * 32, j0 = blockIdx.x * 32;
  const int tx = threadIdx.x & 31, ty = threadIdx.x >> 5; // 32 x 8
#pragma unroll
  for (int rr = 0; rr < 32; rr += 8)
    tile[ty + rr][tx] = x2[((size_t)b * 1024 + j0 + ty + rr) * 1024 + h0 + tx];
  __syncthreads();
  const int mlev = h0 >> 8, dd0 = h0 & 255;
#pragma unroll
  for (int rr = 0; rr < 32; rr += 8) {
    int dd = dd0 + ty + rr;
    vT[((size_t)(b * 4 + mlev) * 256 + dd) * 1024 + j0 + tx] =
        f2h(tile[tx][ty + rr]);
  }
}

// ---------------- fp16 projection GEMM via global_load_lds ------------------
// 128x128 tile, BK=32, 4 waves (2x2 of 64x64), 16 MFMA/K-step.
// LDS linear 64B rows; source pre-swizzled c = (lane&3) ^ ((r>>1)&3);
// read chunk g at slot g ^ ((r>>1)&3)  -> balanced 8 lanes/slot.
// Double-buffered, counted vmcnt(4), raw barriers (no vmcnt(0) drain).
__global__ __launch_bounds__(256, 2) void proj_kernel(
    const u16 *__restrict__ Ag, const u16 *__restrict__ Bg,
    const float *__restrict__ fv, u16 *__restrict__ outk, int usefv) {
  __shared__ u16 As[2][128 * 32], Bs[2][128 * 32]; // 8KB per buf
  const int t = threadIdx.x;
  const int lane = t & 63, wid = t >> 6;
  const int l16 = lane & 15, g = lane >> 4;
  const int wr = wid >> 1, wc = wid & 1;
  const int bm = blockIdx.x, bn = blockIdx.y;

  f32x4 acc[4][4] = {};

  // gllds lane geometry: part i in {0,1}: rows 32*wid + 16*i + (lane>>2)
  const int rA0 = 32 * wid + (lane >> 2), rA1 = rA0 + 16;
  const int cA0 = (lane & 3) ^ ((rA0 >> 1) & 3);
  const int cA1 = (lane & 3) ^ ((rA1 >> 1) & 3);
  const u16 *srcA0 = Ag + (size_t)(bm * 128 + rA0) * 1024 + cA0 * 8;
  const u16 *srcA1 = Ag + (size_t)(bm * 128 + rA1) * 1024 + cA1 * 8;
  const u16 *srcB0 = Bg + (size_t)(bn * 128 + rA0) * 1024 + cA0 * 8;
  const u16 *srcB1 = Bg + (size_t)(bn * 128 + rA1) * 1024 + cA1 * 8;
  const int dst0 = wid * 1024, dst1 = wid * 1024 + 512; // elem offsets

  // prologue: issue K-step 0 into buf 0
  gl16(srcA0, &As[0][dst0]);
  gl16(srcA1, &As[0][dst1]);
  gl16(srcB0, &Bs[0][dst0]);
  gl16(srcB1, &Bs[0][dst1]);

  for (int k0 = 0; k0 < 32; ++k0) {
    const int cur = k0 & 1;
    if (k0 < 31) { // issue next K-step into other buffer
      const int kel = (k0 + 1) * 32, nb = cur ^ 1;
      gl16(srcA0 + kel, &As[nb][dst0]);
      gl16(srcA1 + kel, &As[nb][dst1]);
      gl16(srcB0 + kel, &Bs[nb][dst0]);
      gl16(srcB1 + kel, &Bs[nb][dst1]);
      asm volatile("s_waitcnt vmcnt(4)" ::: "memory");
    } else {
      asm volatile("s_waitcnt vmcnt(0)" ::: "memory");
    }
    __builtin_amdgcn_s_barrier(); // tile k0 ready in buf cur (all waves)
    asm volatile("" ::: "memory");

    u16x8 af[4], bf[4];
#pragma unroll
    for (int mf = 0; mf < 4; ++mf) {
      int r = wr * 64 + mf * 16 + l16;
      af[mf] = *(const u16x8 *)(&As[cur][0] + r * 32 + ((g ^ ((r >> 1) & 3)) * 8));
    }
#pragma unroll
    for (int nf = 0; nf < 4; ++nf) {
      int r = wc * 64 + nf * 16 + l16;
      bf[nf] = *(const u16x8 *)(&Bs[cur][0] + r * 32 + ((g ^ ((r >> 1) & 3)) * 8));
    }
    __builtin_amdgcn_s_setprio(1);
#pragma unroll
    for (int mf = 0; mf < 4; ++mf)
#pragma unroll
      for (int nf = 0; nf < 4; ++nf)
        acc[mf][nf] = mfma16h(af[mf], bf[nf], acc[mf][nf]);
    __builtin_amdgcn_s_setprio(0);
    asm volatile("" ::: "memory");
    __builtin_amdgcn_s_barrier(); // compute done; next buf safe to overwrite
  }

#pragma unroll
  for (int nf = 0; nf < 4; ++nf) {
    int col = bn * 128 + wc * 64 + nf * 16 + l16;
    float f = usefv ? fv[col] : 1.0f;
#pragma unroll
    for (int mf = 0; mf < 4; ++mf) {
      int row0 = bm * 128 + wr * 64 + mf * 16 + g * 4;
#pragma unroll
      for (int q = 0; q < 4; ++q) {
        float v = acc[mf][nf][q];
        v = (v > 0.f ? v : 0.f) * f;
        outk[(size_t)(row0 + q) * 1024 + col] = f2h(v);
      }
    }
  }
}

// ---------------- fused flash attention (fp16, KVBLK=64, defer-max) ---------
// 512 blocks (2/CU), 4 waves x 16 Q rows, reg-prefetch staging, 2 barriers
// and 32+32 MFMA per 64-column tile.
__global__ __launch_bounds__(256, 2) void attn_kernel(
    const u16 *__restrict__ x1k, const u16 *__restrict__ x2k,
    const u16 *__restrict__ vT, const float *__restrict__ bias,
    float *__restrict__ out) {
  __shared__ u16 K2s[64 * 256]; // 32KB: row j 512B; chunk c at slot c^(j&7)
  __shared__ u16 VTs[256 * 64]; // 32KB: row dd 128B; chunk c at slot c^(dd&7)
  __shared__ float biasS[1024];
  __shared__ u16 P[4][16 * 72]; // per-wave P, row stride 144B (9 chunks)

  const int t = threadIdx.x;
  const int lane = t & 63, wid = t >> 6;
  const int l16 = lane & 15, g = lane >> 4;
  const int id = blockIdx.x; // 0..511
  const int xcd = id & 7, idx = id >> 3;
  const int it = idx & 15, pp = idx >> 4;
  const int pair = xcd + 8 * pp;
  const int b = pair >> 2, m = pair & 3;

  for (int j = t; j < 1024; j += 256) biasS[j] = bias[b * 1024 + j];

  const int qrow = it * 64 + wid * 16 + l16;
  const u16 *qsrc = x1k + ((size_t)b * 1024 + qrow) * 1024 + m * 256;
  u16x8 Q[8];
#pragma unroll
  for (int dk = 0; dk < 8; ++dk) Q[dk] = *(const u16x8 *)(qsrc + dk * 32 + g * 8);

  f32x4 acc[16] = {};
  float mrow[4] = {-1e30f, -1e30f, -1e30f, -1e30f};
  float lrow[4] = {0.f, 0.f, 0.f, 0.f};

  // staging: K row sj = t>>2, chunks (t&3)*8+q; V row t, chunks q
  const int sj = t >> 2, cb = (t & 3) * 8;
  const u16 *ksrc = x2k + ((size_t)b * 1024 + sj) * 1024 + m * 256 + cb * 8;
  const u16 *vtsrc = vT + ((size_t)((b * 4 + m) * 256 + t)) * 1024;
  uint32_t koff[8], voff[8];
#pragma unroll
  for (int q = 0; q < 8; ++q) {
    koff[q] = sj * 512 + ((uint32_t)((cb + q) ^ (sj & 7)) << 4);
    voff[q] = t * 128 + ((uint32_t)(q ^ (t & 7)) << 4);
  }

  u16x8 pk[8], pv[8];
#pragma unroll
  for (int q = 0; q < 8; ++q) {
    pk[q] = *(const u16x8 *)(ksrc + q * 8);
    pv[q] = *(const u16x8 *)(vtsrc + q * 8);
  }

  for (int jt = 0; jt < 16; ++jt) {
    __syncthreads(); // prev compute done reading LDS
#pragma unroll
    for (int q = 0; q < 8; ++q) {
      *(u16x8 *)((char *)K2s + koff[q]) = pk[q];
      *(u16x8 *)((char *)VTs + voff[q]) = pv[q];
    }
    __syncthreads(); // staging visible
    if (jt < 15) { // prefetch next tile
      const u16 *k2 = ksrc + (size_t)(jt + 1) * 64 * 1024;
      const u16 *v2 = vtsrc + (jt + 1) * 64;
#pragma unroll
      for (int q = 0; q < 8; ++q) {
        pk[q] = *(const u16x8 *)(k2 + q * 8);
        pv[q] = *(const u16x8 *)(v2 + q * 8);
      }
    }

    // QK^T: rows i=g*4+r, cols j = jh*16+l16; 32 MFMA, 4 indep chains
    f32x4 s[4] = {};
    __builtin_amdgcn_s_setprio(1);
#pragma unroll
    for (int dk = 0; dk < 8; ++dk) {
#pragma unroll
      for (int jh = 0; jh < 4; ++jh) {
        const int j = jh * 16 + l16;
        uint32_t off = j * 512 + ((uint32_t)((dk * 4 + g) ^ (j & 7)) << 4);
        u16x8 kk = *(const u16x8 *)((const char *)K2s + off);
        s[jh] = mfma16h(Q[dk], kk, s[jh]);
      }
    }
    __builtin_amdgcn_s_setprio(0);

    // online softmax with defer-max over 64 cols
    const int j0 = jt * 64;
    float bj[4];
#pragma unroll
    for (int jh = 0; jh < 4; ++jh) bj[jh] = biasS[j0 + jh * 16 + l16];
    float tm[4];
#pragma unroll
    for (int r = 0; r < 4; ++r) {
#pragma unroll
      for (int jh = 0; jh < 4; ++jh) s[jh][r] += bj[jh];
      tm[r] = fmaxf(fmaxf(s[0][r], s[1][r]), fmaxf(s[2][r], s[3][r]));
    }
#pragma unroll
    for (int d = 1; d < 16; d <<= 1)
#pragma unroll
      for (int r = 0; r < 4; ++r) tm[r] = fmaxf(tm[r], __shfl_xor(tm[r], d, 64));
    bool need = false;
#pragma unroll
    for (int r = 0; r < 4; ++r)
      need = need || ((tm[r] - mrow[r]) * L2E > DEFER_THR);
    if (__any((int)need)) {
#pragma unroll
      for (int r = 0; r < 4; ++r) {
        float nm = fmaxf(mrow[r], tm[r]);
        float sc = exp2f((mrow[r] - nm) * L2E);
        mrow[r] = nm;
        lrow[r] *= sc;
#pragma unroll
        for (int nf = 0; nf < 16; ++nf) acc[nf][r] *= sc;
      }
    }
    float p[4][4], rs[4];
#pragma unroll
    for (int r = 0; r < 4; ++r) {
#pragma unroll
      for (int jh = 0; jh < 4; ++jh) p[jh][r] = exp2f((s[jh][r] - mrow[r]) * L2E);
      rs[r] = (p[0][r] + p[1][r]) + (p[2][r] + p[3][r]);
    }
#pragma unroll
    for (int d = 1; d < 16; d <<= 1)
#pragma unroll
      for (int r = 0; r < 4; ++r) rs[r] += __shfl_xor(rs[r], d, 64);
#pragma unroll
    for (int r = 0; r < 4; ++r) lrow[r] += rs[r];

    // P -> per-wave LDS (fp16), then PV (32 MFMA)
    u16 *Pw = &P[wid][0];
#pragma unroll
    for (int jh = 0; jh < 4; ++jh)
#pragma unroll
      for (int r = 0; r < 4; ++r)
        Pw[(g * 4 + r) * 72 + jh * 16 + l16] = f2h(p[jh][r]);
    u16x8 pa[2];
#pragma unroll
    for (int kk = 0; kk < 2; ++kk)
      pa[kk] = *(const u16x8 *)(Pw + l16 * 72 + kk * 32 + g * 8);
    __builtin_amdgcn_s_setprio(1);
#pragma unroll
    for (int nf = 0; nf < 16; ++nf) {
      const int dd = nf * 16 + l16;
#pragma unroll
      for (int kk = 0; kk < 2; ++kk) {
        uint32_t off = dd * 128 + ((uint32_t)((kk * 4 + g) ^ (dd & 7)) << 4);
        u16x8 bb = *(const u16x8 *)((const char *)VTs + off);
        acc[nf] = mfma16h(pa[kk], bb, acc[nf]);
      }
    }
    __builtin_amdgcn_s_setprio(0);
  }

  float inv[4];
#pragma unroll
  for (int r = 0; r < 4; ++r) inv[r] = 1.0f / lrow[r];
#pragma unroll
  for (int nf = 0; nf < 16; ++nf) {
    int col = m * 256 + nf * 16 + l16;
#pragma unroll
    for (int r = 0; r < 4; ++r) {
      int row = it * 64 + wid * 16 + g * 4 + r;
      out[((size_t)b * 1024 + row) * 1024 + col] = acc[nf][r] * inv[r];
    }
  }
}

// ---------------- launch ----------------------------------------------------
extern "C" void kernel_launch(void *const *d_in, const int *in_sizes, int n_in,
                              void *d_out, int out_size, void *d_ws,
                              size_t ws_size, hipStream_t stream) {
  const float *x1_att = (const float *)d_in[0];
  const float *x2_att = (const float *)d_in[1];
  const float *x2 = (const float *)d_in[2];
  const unsigned char *mask = (const unsigned char *)d_in[3];
  const float *W = (const float *)d_in[4];
  const float *fv = (const float *)d_in[5];
  float *out = (float *)d_out;

  const size_t MB = 1u << 20;
  char *ws = (char *)d_ws;
  u16 *x1a16 = (u16 *)(ws + 0 * MB);     // 16MB
  u16 *x2a16 = (u16 *)(ws + 16 * MB);    // 16MB
  u16 *W16 = (u16 *)(ws + 32 * MB);      // 2MB
  u16 *x1k = (u16 *)(ws + 34 * MB);      // 16MB
  u16 *x2k = (u16 *)(ws + 50 * MB);      // 16MB
  u16 *vT = (u16 *)(ws + 66 * MB);       // 16MB
  float *bias = (float *)(ws + 82 * MB); // 32KB

  prep_mask_kernel<<<dim3(1), dim3(256), 0, stream>>>(mask, bias);
  cvt_f16_kernel<<<dim3(4096), dim3(256), 0, stream>>>(x1_att, x1a16);
  cvt_f16_kernel<<<dim3(4096), dim3(256), 0, stream>>>(x2_att, x2a16);
  cvt_f16_kernel<<<dim3(512), dim3(256), 0, stream>>>(W, W16);
  proj_kernel<<<dim3(64, 8), dim3(256), 0, stream>>>(x1a16, W16, fv, x1k, 0);
  proj_kernel<<<dim3(64, 8), dim3(256), 0, stream>>>(x2a16, W16, fv, x2k, 1);
  transpose_v_kernel<<<dim3(32, 32, 8), dim3(256), 0, stream>>>(x2, vT);
  attn_kernel<<<dim3(512), dim3(256), 0, stream>>>(x1k, x2k, vT, bias, out);
}